// Round 4
// baseline (741.918 us; speedup 1.0000x reference)
//
#include <hip/hip_runtime.h>
#include <hip/hip_bf16.h>
#include <float.h>
#include <stdint.h>

// Problem constants
#define NB   64      // batch / num graphs
#define CD   128     // channels / dims
#define OUTD 256
#define NNODE 20000
#define NEDGE 640000

typedef __bf16 bf16x8 __attribute__((ext_vector_type(8)));
typedef float  f32x4  __attribute__((ext_vector_type(4)));

__device__ inline void gl_lds16(const void* g, void* l) {
  __builtin_amdgcn_global_load_lds(
      (const __attribute__((address_space(1))) void*)g,
      (__attribute__((address_space(3))) void*)l, 16, 0, 0);
}

// float atomic max via signed/unsigned int monotonic trick (works for mixed signs)
__device__ inline void atomicMaxF(float* addr, float val) {
  if (val >= 0.f) atomicMax((int*)addr, __float_as_int(val));
  else            atomicMin((unsigned int*)addr, __float_as_uint(val));
}

// ---------------- init: pooled buffers (-FLT_MAX), CSR counters (=0), SN scratch (=0) ----------------
// sn_scratch layout: [0..1151]=v0, [1152..1663]=v1, [1664..1791]=v2, [1792..1795]=ss
__global__ void k_init(float* __restrict__ pooled_v, float* __restrict__ pooled_t,
                       int* __restrict__ cnt, int* __restrict__ fill,
                       float* __restrict__ sn_scratch) {
  const int i = blockIdx.x * 256 + threadIdx.x;   // grid covers 32768
  if (i < NB * CD * 4) pooled_v[i] = -FLT_MAX;
  if (i < NB * CD)     pooled_t[i] = -FLT_MAX;
  if (i < NNODE)       { cnt[i] = 0; fill[i] = 0; }
  if (i < 1796)        sn_scratch[i] = 0.0f;
}

// ---------------- SN stage 1: v = W^T u, 32-row chunks, coalesced, atomicAdd per column ----------------
__global__ __launch_bounds__(256) void k_sn_v(const float* __restrict__ conv_w, const float* __restrict__ conv_u,
                                              const float* __restrict__ fcv_w,  const float* __restrict__ fcv_u,
                                              const float* __restrict__ fct_w,  const float* __restrict__ fct_u,
                                              float* __restrict__ sn) {
  const int bb = blockIdx.x;       // 0..19
  const float* W; const float* u; float* v; int C; int r0;
  if (bb < 4)       { W = conv_w; u = conv_u; v = sn;        C = 1152; r0 = bb * 32; }
  else if (bb < 12) { W = fcv_w;  u = fcv_u;  v = sn + 1152; C = 512;  r0 = (bb - 4) * 32; }
  else              { W = fct_w;  u = fct_u;  v = sn + 1664; C = 128;  r0 = (bb - 12) * 32; }
  const int tid = threadIdx.x;
  float acc[5] = {0.f, 0.f, 0.f, 0.f, 0.f};
  for (int i = r0; i < r0 + 32; ++i) {
    const float ui = u[i];
    const float* row = W + (size_t)i * C;
    #pragma unroll
    for (int t = 0; t < 5; ++t) {
      const int j = tid + t * 256;
      if (j < C) acc[t] += ui * row[j];
    }
  }
  #pragma unroll
  for (int t = 0; t < 5; ++t) {
    const int j = tid + t * 256;
    if (j < C) atomicAdd(&v[j], acc[t]);
  }
}

// ---------------- SN stage 2: ss[m] = ||W v||^2, one wave per row ----------------
__global__ __launch_bounds__(256) void k_sn_w(const float* __restrict__ conv_w,
                                              const float* __restrict__ fcv_w,
                                              const float* __restrict__ fct_w,
                                              float* __restrict__ sn) {
  const int gw = blockIdx.x * 4 + (threadIdx.x >> 6);   // global wave id, 0..639
  const int lane = threadIdx.x & 63;
  const float* W; const float* v; int C, m, row;
  if (gw < 128)      { W = conv_w; v = sn;        C = 1152; m = 0; row = gw; }
  else if (gw < 384) { W = fcv_w;  v = sn + 1152; C = 512;  m = 1; row = gw - 128; }
  else               { W = fct_w;  v = sn + 1664; C = 128;  m = 2; row = gw - 384; }
  const float* wr = W + (size_t)row * C;
  float y = 0.f;
  for (int c = lane; c < C; c += 64) y += wr[c] * v[c];
  #pragma unroll
  for (int s = 32; s > 0; s >>= 1) y += __shfl_xor(y, s, 64);
  if (lane == 0) atomicAdd(&sn[1792 + m], y * y);
}

// ---------------- SN stage 3: inv_sigma[m] = (||v||+eps)/||Wv|| ----------------
__global__ __launch_bounds__(256) void k_sn_fin(const float* __restrict__ sn, float* __restrict__ inv_sigma) {
  __shared__ float red[256];
  const int tid = threadIdx.x;
  const int off[4] = {0, 1152, 1664, 1792};
  for (int m = 0; m < 3; ++m) {
    const int C = off[m + 1] - off[m];
    float ss = 0.f;
    for (int j = tid; j < C; j += 256) { const float a = sn[off[m] + j]; ss += a * a; }
    red[tid] = ss; __syncthreads();
    for (int s = 128; s > 0; s >>= 1) { if (tid < s) red[tid] += red[tid + s]; __syncthreads(); }
    if (tid == 0) inv_sigma[m] = (sqrtf(red[0]) + 1e-12f) / sqrtf(sn[1792 + m]);
    __syncthreads();
  }
}

// ---------------- pack conv weights: Bt[c][pos*128+ci] = conv_w[c][ci][ky][kx]/sigma  (bf16) ----------------
__global__ void k_pack(const float* __restrict__ conv_w, const float* __restrict__ inv_sigma,
                       __hip_bfloat16* __restrict__ Bt) {
  const int idx = blockIdx.x * 256 + threadIdx.x;
  if (idx >= 128 * 1152) return;
  const int c = idx / 1152;
  const int k = idx - c * 1152;
  const int pos = k >> 7, ci = k & 127;
  Bt[idx] = __float2bfloat16(conv_w[(size_t)c * 1152 + ci * 9 + pos] * inv_sigma[0]);
}

// ---------------- NCHW f32 -> NHWC bf16 transpose ----------------
__global__ __launch_bounds__(256) void k_transpose(const float* __restrict__ vis,
                                                   __hip_bfloat16* __restrict__ visT) {
  __shared__ float tile[32][33];
  const int t = blockIdx.x;          // 0..7 : cblk(4) x xblk(2)
  const int cblk = t >> 1, xblk = t & 1;
  const int by = blockIdx.y;         // b*64 + y
  const int b = by >> 6, y = by & 63;
  const int tx = threadIdx.x, ty = threadIdx.y;   // 32 x 8
  const float* src = vis + (size_t)b * 128 * 4096 + (size_t)y * 64;
  #pragma unroll
  for (int i = 0; i < 4; ++i) {
    const int c = (cblk << 5) + ty + (i << 3);
    tile[ty + (i << 3)][tx] = src[(size_t)c * 4096 + (xblk << 5) + tx];
  }
  __syncthreads();
  #pragma unroll
  for (int i = 0; i < 4; ++i) {
    const int x = (xblk << 5) + ty + (i << 3);
    const int c = (cblk << 5) + tx;
    visT[(((size_t)by << 6) + x) * 128 + c] = __float2bfloat16(tile[tx][ty + (i << 3)]);
  }
}

// ---------------- fused conv3x3 + bias + leaky + 31x31 maxpool (implicit GEMM, bf16 MFMA) ----------------
// Tile: M=128 (2 rows x 64 px), N=128 cout, BK=64 (one conv tap per chunk), 18 chunks.
// LDS: [sub(8)][row/n(128)][8 bf16] for A and B. 4 blocks/CU via launch_bounds(256,4).
__global__ __launch_bounds__(256, 4) void k_conv(const __hip_bfloat16* __restrict__ visT,
                                                 const __hip_bfloat16* __restrict__ Bt,
                                                 const float* __restrict__ conv_b,
                                                 float* __restrict__ pooled_v) {
  __shared__ bf16x8 lds_a[1024];   // 16 KB
  __shared__ bf16x8 lds_b[1024];   // 16 KB
  const int bx = blockIdx.x;
  const int b = bx / 31;
  const int y0 = (bx - b * 31) * 2;
  const int tid = threadIdx.x;
  const int wave = tid >> 6, lane = tid & 63;
  const int quad = lane >> 4, l15 = lane & 15;

  f32x4 acc[8][2];
  #pragma unroll
  for (int i = 0; i < 8; ++i) {
    acc[i][0] = f32x4{0.f, 0.f, 0.f, 0.f};
    acc[i][1] = f32x4{0.f, 0.f, 0.f, 0.f};
  }

  const int xA = lane < 62 ? lane : 61;                    // clamp pad pixels
  const __hip_bfloat16* visB = visT + ((size_t)b << 19);   // b*64*64*128
  const __hip_bfloat16* aRow0 = visB + (((y0 + 0) << 6) + xA) * 128;
  const __hip_bfloat16* aRow1 = visB + (((y0 + 1) << 6) + xA) * 128;
  const __hip_bfloat16* bRow0 = Bt + (size_t)lane * 1152;
  const __hip_bfloat16* bRow1 = Bt + (size_t)(64 + lane) * 1152;
  const int s0 = wave << 1;                 // this wave stages subchunks s0, s0+1
  bf16x8* ldsA0 = &lds_a[s0 << 7];
  bf16x8* ldsB0 = &lds_b[s0 << 7];

  for (int ky = 0; ky < 3; ++ky) {
    for (int kx = 0; kx < 3; ++kx) {
      const int aO = (ky << 13) + (kx << 7);    // (ky*64+kx)*128 halves
      const int bO = (ky * 3 + kx) << 7;        // pos*128
      #pragma unroll
      for (int halfk = 0; halfk < 2; ++halfk) {
        const int kA = aO + (halfk << 6) + (s0 << 3);
        const int kB = bO + (halfk << 6) + (s0 << 3);
        gl_lds16(aRow0 + kA,      ldsA0);
        gl_lds16(aRow1 + kA,      ldsA0 + 64);
        gl_lds16(aRow0 + kA + 8,  ldsA0 + 128);
        gl_lds16(aRow1 + kA + 8,  ldsA0 + 192);
        gl_lds16(bRow0 + kB,      ldsB0);
        gl_lds16(bRow1 + kB,      ldsB0 + 64);
        gl_lds16(bRow0 + kB + 8,  ldsB0 + 128);
        gl_lds16(bRow1 + kB + 8,  ldsB0 + 192);
        __syncthreads();
        const bf16x8 b00 = lds_b[(quad << 7) + (wave << 5) + l15];
        const bf16x8 b01 = lds_b[(quad << 7) + (wave << 5) + 16 + l15];
        const bf16x8 b10 = lds_b[((4 + quad) << 7) + (wave << 5) + l15];
        const bf16x8 b11 = lds_b[((4 + quad) << 7) + (wave << 5) + 16 + l15];
        #pragma unroll
        for (int mt = 0; mt < 8; ++mt) {
          const bf16x8 a0 = lds_a[(quad << 7) + (mt << 4) + l15];
          const bf16x8 a1 = lds_a[((4 + quad) << 7) + (mt << 4) + l15];
          acc[mt][0] = __builtin_amdgcn_mfma_f32_16x16x32_bf16(a0, b00, acc[mt][0], 0, 0, 0);
          acc[mt][1] = __builtin_amdgcn_mfma_f32_16x16x32_bf16(a0, b01, acc[mt][1], 0, 0, 0);
          acc[mt][0] = __builtin_amdgcn_mfma_f32_16x16x32_bf16(a1, b10, acc[mt][0], 0, 0, 0);
          acc[mt][1] = __builtin_amdgcn_mfma_f32_16x16x32_bf16(a1, b11, acc[mt][1], 0, 0, 0);
        }
        __syncthreads();
      }
    }
  }

  // epilogue: bias + leaky + pool-max. C layout: n = nbase + l15, m = mt*16 + quad*4 + r.
  const float cb0 = conv_b[(wave << 5) + l15];
  const float cb1 = conv_b[(wave << 5) + 16 + l15];
  float pmax[2][2][2];
  #pragma unroll
  for (int i = 0; i < 8; ++i) (&pmax[0][0][0])[i] = -FLT_MAX;

  #pragma unroll
  for (int mt = 0; mt < 8; ++mt) {
    const int py = (y0 + (mt >> 2)) >= 31 ? 1 : 0;
    #pragma unroll
    for (int r = 0; r < 4; ++r) {
      const int x = ((mt & 3) << 4) + (quad << 2) + r;
      if (x < 62) {
        const int px = x >= 31 ? 1 : 0;
        float v0 = acc[mt][0][r] + cb0;  v0 = v0 >= 0.f ? v0 : 0.2f * v0;
        float v1 = acc[mt][1][r] + cb1;  v1 = v1 >= 0.f ? v1 : 0.2f * v1;
        pmax[0][py][px] = fmaxf(pmax[0][py][px], v0);
        pmax[1][py][px] = fmaxf(pmax[1][py][px], v1);
      }
    }
  }
  #pragma unroll
  for (int nt = 0; nt < 2; ++nt)
    #pragma unroll
    for (int py = 0; py < 2; ++py)
      #pragma unroll
      for (int px = 0; px < 2; ++px) {
        float v = pmax[nt][py][px];
        v = fmaxf(v, __shfl_xor(v, 16, 64));
        v = fmaxf(v, __shfl_xor(v, 32, 64));
        if (quad == 0) {
          const int n = (wave << 5) + (nt << 4) + l15;
          atomicMaxF(&pooled_v[(size_t)b * 512 + n * 4 + py * 2 + px], v);
        }
      }
}

// ---------------- vision FC (spectral-normed) ----------------
__global__ __launch_bounds__(256) void k_fcv(const float* __restrict__ pooled_v, const float* __restrict__ fcv_w,
                                             const float* __restrict__ fcv_b, const float* __restrict__ inv_sigma,
                                             float* __restrict__ out) {
  __shared__ float xr[512];
  const int b = blockIdx.x, tid = threadIdx.x;
  for (int f = tid; f < 512; f += 256) xr[f] = pooled_v[b * 512 + f];
  __syncthreads();
  float a = 0.f;
  const float* wr = fcv_w + (size_t)tid * 512;
  for (int f = 0; f < 512; ++f) a += xr[f] * wr[f];
  out[b * 256 + tid] = a * inv_sigma[1] + fcv_b[tid];
}

// ---------------- topo head: CSR build ----------------
__global__ void k_deg(const int* __restrict__ dst, int* __restrict__ cnt) {
  const int e = blockIdx.x * 256 + threadIdx.x;
  if (e < NEDGE) atomicAdd(&cnt[dst[e]], 1);
}

// exclusive prefix sum of cnt -> offset (single block, 256 threads x 79 nodes each)
__global__ __launch_bounds__(256) void k_scan(const int* __restrict__ cnt, int* __restrict__ offset) {
  __shared__ int red[256];
  const int tid = threadIdx.x;
  const int n0 = tid * 79;
  const int n1 = (n0 + 79 < NNODE) ? n0 + 79 : NNODE;
  int s = 0;
  for (int n = n0; n < n1; ++n) s += cnt[n];
  red[tid] = s; __syncthreads();
  for (int d = 1; d < 256; d <<= 1) {
    int v = (tid >= d) ? red[tid - d] : 0;
    __syncthreads();
    red[tid] += v;
    __syncthreads();
  }
  int run = (tid == 0) ? 0 : red[tid - 1];
  for (int n = n0; n < n1; ++n) { offset[n] = run; run += cnt[n]; }
}

__global__ void k_bucket(const int* __restrict__ src, const int* __restrict__ dst,
                         const int* __restrict__ offset, int* __restrict__ fill,
                         int* __restrict__ sorted_src) {
  const int e = blockIdx.x * 256 + threadIdx.x;
  if (e >= NEDGE) return;
  const int t = dst[e];
  const int pos = atomicAdd(&fill[t], 1);
  sorted_src[offset[t] + pos] = src[e];
}

__global__ void k_dis(const int* __restrict__ cnt, float* __restrict__ dis) {
  const int n = blockIdx.x * 256 + threadIdx.x;
  if (n < NNODE) dis[n] = rsqrtf((float)(cnt[n] + 1));
}

__global__ __launch_bounds__(256) void k_xw(const float* __restrict__ topo, const float* __restrict__ gcn_w,
                                            float* __restrict__ xw) {
  __shared__ float w[128 * 128];
  const int tid = threadIdx.x;
  for (int i = tid; i < 16384; i += 256) w[i] = gcn_w[i];
  __syncthreads();
  const int n0 = blockIdx.x * 64;
  const int j = tid & 127, half = tid >> 7;
  for (int nn = half; nn < 64; nn += 2) {
    const int n = n0 + nn;
    if (n >= NNODE) break;
    const float* tr = topo + (size_t)n * 128;
    float a = 0.f;
    for (int d = 0; d < 128; ++d) a += tr[d] * w[d * 128 + j];
    xw[(size_t)n * 128 + j] = a;
  }
}

// ---------------- GCN gather (CSR) + fused leaky + global max pool ----------------
__global__ __launch_bounds__(128) void k_gather(const int* __restrict__ sorted_src,
                                                const int* __restrict__ offset, const int* __restrict__ cnt,
                                                const float* __restrict__ dis, const float* __restrict__ xw,
                                                const float* __restrict__ gcn_b, const int* __restrict__ batch,
                                                float* __restrict__ pooled_t) {
  const int n = blockIdx.x;
  const int d = threadIdx.x;
  const int e0 = offset[n], ne = cnt[n];
  const float dn = dis[n];
  float acc = dn * xw[(size_t)n * 128 + d];   // self-loop (one dn factored outside)
  int e = 0;
  for (; e + 4 <= ne; e += 4) {
    const int s0 = sorted_src[e0 + e + 0];
    const int s1 = sorted_src[e0 + e + 1];
    const int s2 = sorted_src[e0 + e + 2];
    const int s3 = sorted_src[e0 + e + 3];
    const float x0 = xw[(size_t)s0 * 128 + d];
    const float x1 = xw[(size_t)s1 * 128 + d];
    const float x2 = xw[(size_t)s2 * 128 + d];
    const float x3 = xw[(size_t)s3 * 128 + d];
    acc += dis[s0] * x0 + dis[s1] * x1 + dis[s2] * x2 + dis[s3] * x3;
  }
  for (; e < ne; ++e) {
    const int s = sorted_src[e0 + e];
    acc += dis[s] * xw[(size_t)s * 128 + d];
  }
  float v = gcn_b[d] + dn * acc;
  v = v >= 0.f ? v : 0.2f * v;
  atomicMaxF(&pooled_t[batch[n] * 128 + d], v);
}

__global__ __launch_bounds__(256) void k_fct(const float* __restrict__ pooled_t, const float* __restrict__ fct_w,
                                             const float* __restrict__ fct_b, const float* __restrict__ inv_sigma,
                                             float* __restrict__ out) {
  __shared__ float xr[128];
  const int b = blockIdx.x, tid = threadIdx.x;
  if (tid < 128) xr[tid] = pooled_t[b * 128 + tid];
  __syncthreads();
  float a = 0.f;
  const float* wr = fct_w + (size_t)tid * 128;
  for (int f = 0; f < 128; ++f) a += xr[f] * wr[f];
  out[NB * 256 + b * 256 + tid] = a * inv_sigma[2] + fct_b[tid];
}

extern "C" void kernel_launch(void* const* d_in, const int* in_sizes, int n_in,
                              void* d_out, int out_size, void* d_ws, size_t ws_size,
                              hipStream_t stream) {
  const float* vis    = (const float*)d_in[0];
  const float* topo   = (const float*)d_in[1];
  const int*   eidx   = (const int*)d_in[2];
  const int*   batch  = (const int*)d_in[3];
  const float* conv_w = (const float*)d_in[4];
  const float* conv_b = (const float*)d_in[5];
  const float* conv_u = (const float*)d_in[6];
  const float* fcv_w  = (const float*)d_in[7];
  const float* fcv_b  = (const float*)d_in[8];
  const float* fcv_u  = (const float*)d_in[9];
  const float* gcn_w  = (const float*)d_in[10];
  const float* gcn_b  = (const float*)d_in[11];
  const float* fct_w  = (const float*)d_in[12];
  const float* fct_b  = (const float*)d_in[13];
  const float* fct_u  = (const float*)d_in[14];
  float* out = (float*)d_out;

  char* p = (char*)d_ws;
  float* inv_sigma  = (float*)p; p += 256;
  float* sn_scratch = (float*)p; p += 1796 * 4 + 240;           // v0,v1,v2,ss (pad to 16B)
  float* pooled_v   = (float*)p; p += (size_t)NB * 512 * 4;     // 131072
  float* pooled_t   = (float*)p; p += (size_t)NB * 128 * 4;     // 32768
  int*   cnt        = (int*)p;   p += (size_t)NNODE * 4;
  int*   offset     = (int*)p;   p += (size_t)NNODE * 4;
  int*   fill       = (int*)p;   p += (size_t)NNODE * 4;
  float* dis        = (float*)p; p += (size_t)NNODE * 4;
  int*   sorted_src = (int*)p;   p += (size_t)NEDGE * 4;
  float* xw         = (float*)p; p += (size_t)NNODE * 128 * 4;
  __hip_bfloat16* Bt = (__hip_bfloat16*)p; p += (size_t)128 * 1152 * 2;
  p = (char*)(((uintptr_t)p + 255) & ~(uintptr_t)255);
  __hip_bfloat16* visT = (__hip_bfloat16*)p;                    // 64 MB

  // init + spectral norm (parallel 3-stage)
  hipLaunchKernelGGL(k_init,      dim3(128),     dim3(256),   0, stream, pooled_v, pooled_t, cnt, fill, sn_scratch);
  hipLaunchKernelGGL(k_sn_v,      dim3(20),      dim3(256),   0, stream, conv_w, conv_u, fcv_w, fcv_u, fct_w, fct_u, sn_scratch);
  hipLaunchKernelGGL(k_sn_w,      dim3(160),     dim3(256),   0, stream, conv_w, fcv_w, fct_w, sn_scratch);
  hipLaunchKernelGGL(k_sn_fin,    dim3(1),       dim3(256),   0, stream, sn_scratch, inv_sigma);
  // vision head
  hipLaunchKernelGGL(k_pack,      dim3(576),     dim3(256),   0, stream, conv_w, inv_sigma, Bt);
  hipLaunchKernelGGL(k_transpose, dim3(8, 4096), dim3(32, 8), 0, stream, vis, visT);
  hipLaunchKernelGGL(k_conv,      dim3(64 * 31), dim3(256),   0, stream, visT, Bt, conv_b, pooled_v);
  hipLaunchKernelGGL(k_fcv,       dim3(64),      dim3(256),   0, stream, pooled_v, fcv_w, fcv_b, inv_sigma, out);
  // topo head: CSR build + gather (pool fused)
  hipLaunchKernelGGL(k_deg,       dim3(2500),    dim3(256),   0, stream, eidx + NEDGE, cnt);
  hipLaunchKernelGGL(k_scan,      dim3(1),       dim3(256),   0, stream, cnt, offset);
  hipLaunchKernelGGL(k_bucket,    dim3(2500),    dim3(256),   0, stream, eidx, eidx + NEDGE, offset, fill, sorted_src);
  hipLaunchKernelGGL(k_dis,       dim3(79),      dim3(256),   0, stream, cnt, dis);
  hipLaunchKernelGGL(k_xw,        dim3(313),     dim3(256),   0, stream, topo, gcn_w, xw);
  hipLaunchKernelGGL(k_gather,    dim3(NNODE),   dim3(128),   0, stream, sorted_src, offset, cnt, dis, xw, gcn_b, batch, pooled_t);
  hipLaunchKernelGGL(k_fct,       dim3(64),      dim3(256),   0, stream, pooled_t, fct_w, fct_b, inv_sigma, out);
}

// Round 5
// 646.895 us; speedup vs baseline: 1.1469x; 1.1469x over previous
//
#include <hip/hip_runtime.h>
#include <hip/hip_bf16.h>
#include <float.h>
#include <stdint.h>

// Problem constants
#define NB   64      // batch / num graphs
#define CD   128     // channels / dims
#define OUTD 256
#define NNODE 20000
#define NEDGE 640000

typedef __bf16 bf16x8 __attribute__((ext_vector_type(8)));
typedef float  f32x4  __attribute__((ext_vector_type(4)));

__device__ inline void gl_lds16(const void* g, void* l) {
  __builtin_amdgcn_global_load_lds(
      (const __attribute__((address_space(1))) void*)g,
      (__attribute__((address_space(3))) void*)l, 16, 0, 0);
}

// float atomic max via signed/unsigned int monotonic trick (works for mixed signs)
__device__ inline void atomicMaxF(float* addr, float val) {
  if (val >= 0.f) atomicMax((int*)addr, __float_as_int(val));
  else            atomicMin((unsigned int*)addr, __float_as_uint(val));
}

// ---------------- init: pooled buffers (-FLT_MAX), CSR counters (=0), SN scratch (=0) ----------------
// sn_scratch layout: [0..1151]=v0, [1152..1663]=v1, [1664..1791]=v2, [1792..1795]=ss
__global__ void k_init(float* __restrict__ pooled_v, float* __restrict__ pooled_t,
                       int* __restrict__ cnt, int* __restrict__ fill,
                       float* __restrict__ sn_scratch) {
  const int i = blockIdx.x * 256 + threadIdx.x;   // grid covers 32768
  if (i < NB * CD * 4) pooled_v[i] = -FLT_MAX;
  if (i < NB * CD)     pooled_t[i] = -FLT_MAX;
  if (i < NNODE)       { cnt[i] = 0; fill[i] = 0; }
  if (i < 1796)        sn_scratch[i] = 0.0f;
}

// ---------------- SN stage 1: v = W^T u, 32-row chunks, coalesced, atomicAdd per column ----------------
__global__ __launch_bounds__(256) void k_sn_v(const float* __restrict__ conv_w, const float* __restrict__ conv_u,
                                              const float* __restrict__ fcv_w,  const float* __restrict__ fcv_u,
                                              const float* __restrict__ fct_w,  const float* __restrict__ fct_u,
                                              float* __restrict__ sn) {
  const int bb = blockIdx.x;       // 0..19
  const float* W; const float* u; float* v; int C; int r0;
  if (bb < 4)       { W = conv_w; u = conv_u; v = sn;        C = 1152; r0 = bb * 32; }
  else if (bb < 12) { W = fcv_w;  u = fcv_u;  v = sn + 1152; C = 512;  r0 = (bb - 4) * 32; }
  else              { W = fct_w;  u = fct_u;  v = sn + 1664; C = 128;  r0 = (bb - 12) * 32; }
  const int tid = threadIdx.x;
  float acc[5] = {0.f, 0.f, 0.f, 0.f, 0.f};
  for (int i = r0; i < r0 + 32; ++i) {
    const float ui = u[i];
    const float* row = W + (size_t)i * C;
    #pragma unroll
    for (int t = 0; t < 5; ++t) {
      const int j = tid + t * 256;
      if (j < C) acc[t] += ui * row[j];
    }
  }
  #pragma unroll
  for (int t = 0; t < 5; ++t) {
    const int j = tid + t * 256;
    if (j < C) atomicAdd(&v[j], acc[t]);
  }
}

// ---------------- SN stage 2: ss[m] = ||W v||^2, one wave per row ----------------
__global__ __launch_bounds__(256) void k_sn_w(const float* __restrict__ conv_w,
                                              const float* __restrict__ fcv_w,
                                              const float* __restrict__ fct_w,
                                              float* __restrict__ sn) {
  const int gw = blockIdx.x * 4 + (threadIdx.x >> 6);   // global wave id, 0..639
  const int lane = threadIdx.x & 63;
  const float* W; const float* v; int C, m, row;
  if (gw < 128)      { W = conv_w; v = sn;        C = 1152; m = 0; row = gw; }
  else if (gw < 384) { W = fcv_w;  v = sn + 1152; C = 512;  m = 1; row = gw - 128; }
  else               { W = fct_w;  v = sn + 1664; C = 128;  m = 2; row = gw - 384; }
  const float* wr = W + (size_t)row * C;
  float y = 0.f;
  for (int c = lane; c < C; c += 64) y += wr[c] * v[c];
  #pragma unroll
  for (int s = 32; s > 0; s >>= 1) y += __shfl_xor(y, s, 64);
  if (lane == 0) atomicAdd(&sn[1792 + m], y * y);
}

// ---------------- SN stage 3: inv_sigma[m] = (||v||+eps)/||Wv|| ----------------
__global__ __launch_bounds__(256) void k_sn_fin(const float* __restrict__ sn, float* __restrict__ inv_sigma) {
  __shared__ float red[256];
  const int tid = threadIdx.x;
  const int off[4] = {0, 1152, 1664, 1792};
  for (int m = 0; m < 3; ++m) {
    const int C = off[m + 1] - off[m];
    float ss = 0.f;
    for (int j = tid; j < C; j += 256) { const float a = sn[off[m] + j]; ss += a * a; }
    red[tid] = ss; __syncthreads();
    for (int s = 128; s > 0; s >>= 1) { if (tid < s) red[tid] += red[tid + s]; __syncthreads(); }
    if (tid == 0) inv_sigma[m] = (sqrtf(red[0]) + 1e-12f) / sqrtf(sn[1792 + m]);
    __syncthreads();
  }
}

// ---------------- pack conv weights into staging-coalesced frag order ----------------
// Bt2[tap(9)][halfk(2)][sub(8)][n(128)][c8(8)] = conv_w[n][ci=hk*64+s*8+j][tap] / sigma
__global__ void k_pack(const float* __restrict__ conv_w, const float* __restrict__ inv_sigma,
                       __hip_bfloat16* __restrict__ Bt2) {
  const int t = blockIdx.x * 256 + threadIdx.x;
  if (t >= 147456) return;
  const int j = t & 7, n = (t >> 3) & 127, s = (t >> 10) & 7, hk = (t >> 13) & 1, tap = t >> 14;
  const int ci = hk * 64 + s * 8 + j;
  Bt2[t] = __float2bfloat16(conv_w[n * 1152 + ci * 9 + tap] * inv_sigma[0]);
}

// ---------------- NCHW f32 -> tiled bf16: visT2[b][y][g=c/8][x(64)][c8(8)] ----------------
__global__ __launch_bounds__(256) void k_transpose(const float* __restrict__ vis,
                                                   __hip_bfloat16* __restrict__ visT2) {
  __shared__ float tile[8192];            // [c(128)][x(64)]
  const int by = blockIdx.x;              // b*64 + y
  const int b = by >> 6, y = by & 63;
  const int t = threadIdx.x;
  const float* src = vis + (size_t)b * 524288 + (size_t)(t >> 6) * 4096 + y * 64 + (t & 63);
  #pragma unroll
  for (int i = 0; i < 32; ++i)            // c = i*4 + (t>>6), x = t&63
    tile[(i * 4 + (t >> 6)) * 64 + (t & 63)] = src[(size_t)i * 4 * 4096];
  __syncthreads();
  bf16x8* dst = (bf16x8*)(visT2 + ((size_t)by << 13));   // by*16*512 elems
  #pragma unroll
  for (int k = 0; k < 4; ++k) {
    const int j = k * 256 + t;            // chunk: g = j>>6, x = j&63
    const int g = j >> 6, x = j & 63;
    union { bf16x8 v; __hip_bfloat16 h[8]; } u;
    #pragma unroll
    for (int cc = 0; cc < 8; ++cc)
      u.h[cc] = __float2bfloat16(tile[(g * 8 + cc) * 64 + x]);
    dst[j] = u.v;
  }
}

// ---------------- fused conv3x3 + bias + leaky + 31x31 maxpool (implicit GEMM, bf16 MFMA) ----------------
// Tile: M=128 (2 rows x 64 px), N=128 cout, BK=64. All staging loads are contiguous
// 1KB wave-transactions thanks to visT2/Bt2 pre-tiling (R4 was VMEM-sector-bound on gathers).
__global__ __launch_bounds__(256, 4) void k_conv(const __hip_bfloat16* __restrict__ visT2,
                                                 const __hip_bfloat16* __restrict__ Bt2,
                                                 const float* __restrict__ conv_b,
                                                 float* __restrict__ pooled_v) {
  __shared__ bf16x8 lds_a[1024];   // 16 KB  [sub(8)][m(128)]
  __shared__ bf16x8 lds_b[1024];   // 16 KB  [sub(8)][n(128)]
  const int bx = blockIdx.x;
  const int b = bx / 31;
  const int y0 = (bx - b * 31) * 2;
  const int tid = threadIdx.x;
  const int wave = tid >> 6, lane = tid & 63;
  const int quad = lane >> 4, l15 = lane & 15;

  f32x4 acc[8][2];
  #pragma unroll
  for (int i = 0; i < 8; ++i) {
    acc[i][0] = f32x4{0.f, 0.f, 0.f, 0.f};
    acc[i][1] = f32x4{0.f, 0.f, 0.f, 0.f};
  }

  const __hip_bfloat16* vb = visT2 + ((size_t)b << 19);   // b*64*16*512
  const int s0 = wave << 1;                 // this wave stages subchunks s0, s0+1
  bf16x8* ldsA0 = &lds_a[s0 << 7];
  bf16x8* ldsB0 = &lds_b[s0 << 7];
  const int lane8 = lane << 3;

  for (int ky = 0; ky < 3; ++ky) {
    for (int kx = 0; kx < 3; ++kx) {
      const int tap = ky * 3 + kx;
      #pragma unroll
      for (int hk = 0; hk < 2; ++hk) {
        // A: visT2 row-group (y, g=hk*8+s); kx shift = +kx*8 elems; lanes contiguous.
        const __hip_bfloat16* a0p = vb + ((size_t)(((y0 + ky) << 4) + (hk << 3) + s0) << 9) + (kx << 3) + lane8;
        const __hip_bfloat16* a1p = vb + ((size_t)(((y0 + 1 + ky) << 4) + (hk << 3) + s0) << 9) + (kx << 3) + lane8;
        const __hip_bfloat16* bp  = Bt2 + ((size_t)(((tap << 1) + hk) << 3) + s0 << 10) + lane8;
        gl_lds16(a0p,        ldsA0);         // sub s0, m 0..63   (row0)
        gl_lds16(a1p,        ldsA0 + 64);    // sub s0, m 64..127 (row1)
        gl_lds16(a0p + 512,  ldsA0 + 128);   // sub s0+1, row0
        gl_lds16(a1p + 512,  ldsA0 + 192);   // sub s0+1, row1
        gl_lds16(bp,         ldsB0);         // sub s0, n 0..63
        gl_lds16(bp + 512,   ldsB0 + 64);    // sub s0, n 64..127
        gl_lds16(bp + 1024,  ldsB0 + 128);   // sub s0+1, n 0..63
        gl_lds16(bp + 1536,  ldsB0 + 192);   // sub s0+1, n 64..127
        __syncthreads();
        const bf16x8 b00 = lds_b[(quad << 7) + (wave << 5) + l15];
        const bf16x8 b01 = lds_b[(quad << 7) + (wave << 5) + 16 + l15];
        const bf16x8 b10 = lds_b[((4 + quad) << 7) + (wave << 5) + l15];
        const bf16x8 b11 = lds_b[((4 + quad) << 7) + (wave << 5) + 16 + l15];
        #pragma unroll
        for (int mt = 0; mt < 8; ++mt) {
          const bf16x8 a0 = lds_a[(quad << 7) + (mt << 4) + l15];
          const bf16x8 a1 = lds_a[((4 + quad) << 7) + (mt << 4) + l15];
          acc[mt][0] = __builtin_amdgcn_mfma_f32_16x16x32_bf16(a0, b00, acc[mt][0], 0, 0, 0);
          acc[mt][1] = __builtin_amdgcn_mfma_f32_16x16x32_bf16(a0, b01, acc[mt][1], 0, 0, 0);
          acc[mt][0] = __builtin_amdgcn_mfma_f32_16x16x32_bf16(a1, b10, acc[mt][0], 0, 0, 0);
          acc[mt][1] = __builtin_amdgcn_mfma_f32_16x16x32_bf16(a1, b11, acc[mt][1], 0, 0, 0);
        }
        __syncthreads();
      }
    }
  }

  // epilogue: bias + leaky + pool-max. C layout: n = nbase + l15, m = mt*16 + quad*4 + r.
  const float cb0 = conv_b[(wave << 5) + l15];
  const float cb1 = conv_b[(wave << 5) + 16 + l15];
  float pmax[2][2][2];
  #pragma unroll
  for (int i = 0; i < 8; ++i) (&pmax[0][0][0])[i] = -FLT_MAX;

  #pragma unroll
  for (int mt = 0; mt < 8; ++mt) {
    const int py = (y0 + (mt >> 2)) >= 31 ? 1 : 0;
    #pragma unroll
    for (int r = 0; r < 4; ++r) {
      const int x = ((mt & 3) << 4) + (quad << 2) + r;
      if (x < 62) {
        const int px = x >= 31 ? 1 : 0;
        float v0 = acc[mt][0][r] + cb0;  v0 = v0 >= 0.f ? v0 : 0.2f * v0;
        float v1 = acc[mt][1][r] + cb1;  v1 = v1 >= 0.f ? v1 : 0.2f * v1;
        pmax[0][py][px] = fmaxf(pmax[0][py][px], v0);
        pmax[1][py][px] = fmaxf(pmax[1][py][px], v1);
      }
    }
  }
  #pragma unroll
  for (int nt = 0; nt < 2; ++nt)
    #pragma unroll
    for (int py = 0; py < 2; ++py)
      #pragma unroll
      for (int px = 0; px < 2; ++px) {
        float v = pmax[nt][py][px];
        v = fmaxf(v, __shfl_xor(v, 16, 64));
        v = fmaxf(v, __shfl_xor(v, 32, 64));
        if (quad == 0) {
          const int n = (wave << 5) + (nt << 4) + l15;
          atomicMaxF(&pooled_v[(size_t)b * 512 + n * 4 + py * 2 + px], v);
        }
      }
}

// ---------------- vision FC (spectral-normed) ----------------
__global__ __launch_bounds__(256) void k_fcv(const float* __restrict__ pooled_v, const float* __restrict__ fcv_w,
                                             const float* __restrict__ fcv_b, const float* __restrict__ inv_sigma,
                                             float* __restrict__ out) {
  __shared__ float xr[512];
  const int b = blockIdx.x, tid = threadIdx.x;
  for (int f = tid; f < 512; f += 256) xr[f] = pooled_v[b * 512 + f];
  __syncthreads();
  float a = 0.f;
  const float* wr = fcv_w + (size_t)tid * 512;
  for (int f = 0; f < 512; ++f) a += xr[f] * wr[f];
  out[b * 256 + tid] = a * inv_sigma[1] + fcv_b[tid];
}

// ---------------- topo head: CSR build ----------------
__global__ void k_deg(const int* __restrict__ dst, int* __restrict__ cnt) {
  const int e = blockIdx.x * 256 + threadIdx.x;
  if (e < NEDGE) atomicAdd(&cnt[dst[e]], 1);
}

// exclusive prefix sum of cnt -> offset (single block, 256 threads x 79 nodes each)
__global__ __launch_bounds__(256) void k_scan(const int* __restrict__ cnt, int* __restrict__ offset) {
  __shared__ int red[256];
  const int tid = threadIdx.x;
  const int n0 = tid * 79;
  const int n1 = (n0 + 79 < NNODE) ? n0 + 79 : NNODE;
  int s = 0;
  for (int n = n0; n < n1; ++n) s += cnt[n];
  red[tid] = s; __syncthreads();
  for (int d = 1; d < 256; d <<= 1) {
    int v = (tid >= d) ? red[tid - d] : 0;
    __syncthreads();
    red[tid] += v;
    __syncthreads();
  }
  int run = (tid == 0) ? 0 : red[tid - 1];
  for (int n = n0; n < n1; ++n) { offset[n] = run; run += cnt[n]; }
}

__global__ void k_bucket(const int* __restrict__ src, const int* __restrict__ dst,
                         const int* __restrict__ offset, int* __restrict__ fill,
                         int* __restrict__ sorted_src) {
  const int e = blockIdx.x * 256 + threadIdx.x;
  if (e >= NEDGE) return;
  const int t = dst[e];
  const int pos = atomicAdd(&fill[t], 1);
  sorted_src[offset[t] + pos] = src[e];
}

__global__ void k_dis(const int* __restrict__ cnt, float* __restrict__ dis) {
  const int n = blockIdx.x * 256 + threadIdx.x;
  if (n < NNODE) dis[n] = rsqrtf((float)(cnt[n] + 1));
}

__global__ __launch_bounds__(256) void k_xw(const float* __restrict__ topo, const float* __restrict__ gcn_w,
                                            float* __restrict__ xw) {
  __shared__ float w[128 * 128];
  const int tid = threadIdx.x;
  for (int i = tid; i < 16384; i += 256) w[i] = gcn_w[i];
  __syncthreads();
  const int n0 = blockIdx.x * 64;
  const int j = tid & 127, half = tid >> 7;
  for (int nn = half; nn < 64; nn += 2) {
    const int n = n0 + nn;
    if (n >= NNODE) break;
    const float* tr = topo + (size_t)n * 128;
    float a = 0.f;
    for (int d = 0; d < 128; ++d) a += tr[d] * w[d * 128 + j];
    xw[(size_t)n * 128 + j] = a;
  }
}

// ---------------- GCN gather (CSR, no float atomics): h = leaky(b + dn*(dn*xw[n] + sum dis[s]*xw[s])) ----------------
__global__ __launch_bounds__(128) void k_gather(const int* __restrict__ sorted_src,
                                                const int* __restrict__ offset, const int* __restrict__ cnt,
                                                const float* __restrict__ dis, const float* __restrict__ xw,
                                                const float* __restrict__ gcn_b, float* __restrict__ h) {
  const int n = blockIdx.x;
  const int d = threadIdx.x;
  const int e0 = offset[n], ne = cnt[n];
  const float dn = dis[n];
  float acc = dn * xw[(size_t)n * 128 + d];   // self-loop (one dn factored outside)
  int e = 0;
  for (; e + 4 <= ne; e += 4) {
    const int s0 = sorted_src[e0 + e + 0];
    const int s1 = sorted_src[e0 + e + 1];
    const int s2 = sorted_src[e0 + e + 2];
    const int s3 = sorted_src[e0 + e + 3];
    const float x0 = xw[(size_t)s0 * 128 + d];
    const float x1 = xw[(size_t)s1 * 128 + d];
    const float x2 = xw[(size_t)s2 * 128 + d];
    const float x3 = xw[(size_t)s3 * 128 + d];
    acc += dis[s0] * x0 + dis[s1] * x1 + dis[s2] * x2 + dis[s3] * x3;
  }
  for (; e < ne; ++e) {
    const int s = sorted_src[e0 + e];
    acc += dis[s] * xw[(size_t)s * 128 + d];
  }
  float v = gcn_b[d] + dn * acc;
  v = v >= 0.f ? v : 0.2f * v;
  h[(size_t)n * 128 + d] = v;
}

__global__ void k_pool_t(const float* __restrict__ h, const int* __restrict__ batch,
                         float* __restrict__ pooled_t) {
  const int d = threadIdx.x;           // 128
  const int n0 = blockIdx.x * 32;
  float run = -FLT_MAX;
  int cur = batch[n0];
  for (int i = 0; i < 32; ++i) {
    const int n = n0 + i;
    const int g = batch[n];
    if (g != cur) {
      atomicMaxF(&pooled_t[cur * 128 + d], run);
      run = -FLT_MAX; cur = g;
    }
    run = fmaxf(run, h[(size_t)n * 128 + d]);
  }
  atomicMaxF(&pooled_t[cur * 128 + d], run);
}

__global__ __launch_bounds__(256) void k_fct(const float* __restrict__ pooled_t, const float* __restrict__ fct_w,
                                             const float* __restrict__ fct_b, const float* __restrict__ inv_sigma,
                                             float* __restrict__ out) {
  __shared__ float xr[128];
  const int b = blockIdx.x, tid = threadIdx.x;
  if (tid < 128) xr[tid] = pooled_t[b * 128 + tid];
  __syncthreads();
  float a = 0.f;
  const float* wr = fct_w + (size_t)tid * 128;
  for (int f = 0; f < 128; ++f) a += xr[f] * wr[f];
  out[NB * 256 + b * 256 + tid] = a * inv_sigma[2] + fct_b[tid];
}

extern "C" void kernel_launch(void* const* d_in, const int* in_sizes, int n_in,
                              void* d_out, int out_size, void* d_ws, size_t ws_size,
                              hipStream_t stream) {
  const float* vis    = (const float*)d_in[0];
  const float* topo   = (const float*)d_in[1];
  const int*   eidx   = (const int*)d_in[2];
  const int*   batch  = (const int*)d_in[3];
  const float* conv_w = (const float*)d_in[4];
  const float* conv_b = (const float*)d_in[5];
  const float* conv_u = (const float*)d_in[6];
  const float* fcv_w  = (const float*)d_in[7];
  const float* fcv_b  = (const float*)d_in[8];
  const float* fcv_u  = (const float*)d_in[9];
  const float* gcn_w  = (const float*)d_in[10];
  const float* gcn_b  = (const float*)d_in[11];
  const float* fct_w  = (const float*)d_in[12];
  const float* fct_b  = (const float*)d_in[13];
  const float* fct_u  = (const float*)d_in[14];
  float* out = (float*)d_out;

  char* p = (char*)d_ws;
  float* inv_sigma  = (float*)p; p += 256;
  float* sn_scratch = (float*)p; p += 1796 * 4 + 240;           // v0,v1,v2,ss (pad to 16B)
  float* pooled_v   = (float*)p; p += (size_t)NB * 512 * 4;     // 131072
  float* pooled_t   = (float*)p; p += (size_t)NB * 128 * 4;     // 32768
  int*   cnt        = (int*)p;   p += (size_t)NNODE * 4;
  int*   offset     = (int*)p;   p += (size_t)NNODE * 4;
  int*   fill       = (int*)p;   p += (size_t)NNODE * 4;
  float* dis        = (float*)p; p += (size_t)NNODE * 4;
  int*   sorted_src = (int*)p;   p += (size_t)NEDGE * 4;
  float* xw         = (float*)p; p += (size_t)NNODE * 128 * 4;
  float* h          = (float*)p; p += (size_t)NNODE * 128 * 4;
  __hip_bfloat16* Bt2 = (__hip_bfloat16*)p; p += (size_t)147456 * 2;
  p = (char*)(((uintptr_t)p + 255) & ~(uintptr_t)255);
  __hip_bfloat16* visT2 = (__hip_bfloat16*)p;                   // 64 MB + tail pad (OOB-read slack)

  // init + spectral norm (parallel 3-stage)
  hipLaunchKernelGGL(k_init,      dim3(128),   dim3(256), 0, stream, pooled_v, pooled_t, cnt, fill, sn_scratch);
  hipLaunchKernelGGL(k_sn_v,      dim3(20),    dim3(256), 0, stream, conv_w, conv_u, fcv_w, fcv_u, fct_w, fct_u, sn_scratch);
  hipLaunchKernelGGL(k_sn_w,      dim3(160),   dim3(256), 0, stream, conv_w, fcv_w, fct_w, sn_scratch);
  hipLaunchKernelGGL(k_sn_fin,    dim3(1),     dim3(256), 0, stream, sn_scratch, inv_sigma);
  // vision head
  hipLaunchKernelGGL(k_pack,      dim3(576),   dim3(256), 0, stream, conv_w, inv_sigma, Bt2);
  hipLaunchKernelGGL(k_transpose, dim3(4096),  dim3(256), 0, stream, vis, visT2);
  hipLaunchKernelGGL(k_conv,      dim3(64*31), dim3(256), 0, stream, visT2, Bt2, conv_b, pooled_v);
  hipLaunchKernelGGL(k_fcv,       dim3(64),    dim3(256), 0, stream, pooled_v, fcv_w, fcv_b, inv_sigma, out);
  // topo head: CSR build + gather, separate pool (R4 fusion was a ~20us regression)
  hipLaunchKernelGGL(k_deg,       dim3(2500),  dim3(256), 0, stream, eidx + NEDGE, cnt);
  hipLaunchKernelGGL(k_scan,      dim3(1),     dim3(256), 0, stream, cnt, offset);
  hipLaunchKernelGGL(k_bucket,    dim3(2500),  dim3(256), 0, stream, eidx, eidx + NEDGE, offset, fill, sorted_src);
  hipLaunchKernelGGL(k_dis,       dim3(79),    dim3(256), 0, stream, cnt, dis);
  hipLaunchKernelGGL(k_xw,        dim3(313),   dim3(256), 0, stream, topo, gcn_w, xw);
  hipLaunchKernelGGL(k_gather,    dim3(NNODE), dim3(128), 0, stream, sorted_src, offset, cnt, dis, xw, gcn_b, h);
  hipLaunchKernelGGL(k_pool_t,    dim3(625),   dim3(128), 0, stream, h, batch, pooled_t);
  hipLaunchKernelGGL(k_fct,       dim3(64),    dim3(256), 0, stream, pooled_t, fct_w, fct_b, inv_sigma, out);
}